// Round 14
// baseline (355.202 us; speedup 1.0000x reference)
//
#include <hip/hip_runtime.h>
#include <hip/hip_bf16.h>
#include <math.h>

// Problem dims
#define B_  16
#define S_  4096
#define D_  256
#define H_  512
#define BS_ 65536           // B_*S_
#define BSD_ 16777216L      // BS_*D_
#define CCH 128             // scan chunks
#define LCH 32              // chunk length
#define TPAD 136            // r8 epilogue tile stride (272B row, 16B multiple)

typedef __bf16 bf16;
typedef __bf16 bf16x8 __attribute__((ext_vector_type(8)));
typedef float  f32x4  __attribute__((ext_vector_type(4)));

#define AS1 __attribute__((address_space(1)))
#define AS3 __attribute__((address_space(3)))

__device__ __forceinline__ void gload_lds16(const void* g, void* l) {
  __builtin_amdgcn_global_load_lds((const AS1 void*)g, (AS3 void*)l, 16, 0, 0);
}

// ---- fast transcendentals ----
#if __has_builtin(__builtin_amdgcn_exp2f)
#define EXP2F __builtin_amdgcn_exp2f
#else
#define EXP2F exp2f
#endif
#if __has_builtin(__builtin_amdgcn_rcpf)
#define RCPF __builtin_amdgcn_rcpf
#else
#define RCPF(x) (1.f/(x))
#endif
#define L2E 1.4426950408889634f

__device__ __forceinline__ float fsigmoid(float x) {
  return RCPF(1.f + EXP2F(-L2E * x));
}
__device__ __forceinline__ float ftanh(float x) {
  return 2.f * RCPF(1.f + EXP2F(-2.f * L2E * x)) - 1.f;
}
__device__ __forceinline__ float fsilu(float x) {
  return x * RCPF(1.f + EXP2F(-L2E * x));
}

// ---------------- casts ----------------
__global__ void k_cast_x(const float* __restrict__ x, bf16* __restrict__ xb, int n8) {
  int i = blockIdx.x * blockDim.x + threadIdx.x;
  if (i >= n8) return;
  const float4* p = (const float4*)x + (long)i * 2;
  float4 a = p[0], b = p[1];
  bf16x8 o;
  o[0]=(bf16)a.x; o[1]=(bf16)a.y; o[2]=(bf16)a.z; o[3]=(bf16)a.w;
  o[4]=(bf16)b.x; o[5]=(bf16)b.y; o[6]=(bf16)b.z; o[7]=(bf16)b.w;
  ((bf16x8*)xb)[i] = o;
}

__global__ void k_cast_w(const float* __restrict__ in_w, const float* __restrict__ gate_w,
                         const float* __restrict__ pw_w,
                         bf16* __restrict__ w1, bf16* __restrict__ pw) {
  int i = blockIdx.x * blockDim.x + threadIdx.x;
  const int HD = H_ * D_;           // 131072
  if (i < HD)            w1[i] = (bf16)in_w[i];
  else if (i < 2 * HD)   w1[i] = (bf16)gate_w[i - HD];
  else {
    int j = i - 2 * HD;
    if (j < H_ * H_)     pw[j] = (bf16)pw_w[j];
  }
}

// ======== proj: weight-stationary streaming GEMM (barrier-free main loop) ========
// Hardened vs r13: explicit lgkmcnt(0) between scratch-write and scratch-read
// phases (removes reliance on implicit per-wave DS ordering across exec masks).
// EPI==1 only in this round (bisect: pw uses the known-good r8 kernel below).
template<int KDIM, int EPI, int NBLK, int NCH, int NCOL>
__global__ __launch_bounds__(512, 4)
void k_wgemm(const bf16* __restrict__ A, const bf16* __restrict__ Bw,
             const int* __restrict__ mask,
             const float* __restrict__ bias0, const float* __restrict__ bias1,
             bf16* __restrict__ out0, bf16* __restrict__ out1)
{
  constexpr int NF  = NCOL / 16;
  constexpr int SCS = NCOL + 8;           // 72 -> 144B rows (16B multiple)
  constexpr int K8  = KDIM / 8;
  constexpr int NT  = KDIM / 32;

  extern __shared__ char smem[];
  bf16* Wl = (bf16*)smem;                               // [K8][NCOL][8]
  const int t = threadIdx.x;
  const int w8 = t >> 6, lane = t & 63;
  bf16* sc = (bf16*)(smem + (long)NCOL * KDIM * 2 + w8 * (8 * SCS * 2));

  const int nwg = gridDim.x;                            // %8==0
  const int wg = (blockIdx.x & 7) * (nwg >> 3) + (blockIdx.x >> 3);
  const int n0 = (wg % NBLK) * NCOL;
  const int ms = wg / NBLK;
  const long wbase = (long)ms * (16L * 8 * NCH) + (long)w8 * (16 * NCH);

  // stage weights -> LDS (once per block)
  for (int i = t; i < NCOL * K8; i += 512) {
    const int k8 = i & (K8 - 1), c = i / K8;
    *(bf16x8*)(Wl + k8 * (NCOL * 8) + c * 8) =
        *(const bf16x8*)(Bw + (long)(n0 + c) * KDIM + k8 * 8);
  }
  __syncthreads();                                      // the only block barrier

  const int fr = lane & 15, kq = lane >> 4;
  const bool hside = (EPI != 1) || (n0 < H_);

  float b0[NF], b1g[NF];
#pragma unroll
  for (int nf = 0; nf < NF; ++nf) {
    const int c = n0 + nf * 16 + fr;
    b0[nf]  = hside ? bias0[c] : 0.f;
    b1g[nf] = (!hside) ? bias1[c - H_] : 0.f;
  }

  bf16x8 af[NT];
#define LOADA(m0_)                                                          \
  { const bf16* _p = A + ((m0_) + fr) * (long)KDIM + kq * 8;                \
    _Pragma("unroll")                                                       \
    for (int kt = 0; kt < NT; ++kt) af[kt] = *(const bf16x8*)(_p + kt * 32); }

  LOADA(wbase);
  for (int ch = 0; ch < NCH; ++ch) {
    const long m0 = wbase + ch * 16;
    f32x4 acc[NF];
#pragma unroll
    for (int nf = 0; nf < NF; ++nf) acc[nf] = (f32x4){0.f, 0.f, 0.f, 0.f};
#pragma unroll
    for (int kt = 0; kt < NT; ++kt) {
#pragma unroll
      for (int nf = 0; nf < NF; ++nf) {
        const bf16x8 bfr =
            *(const bf16x8*)&Wl[(kt * 4 + kq) * (NCOL * 8) + (nf * 16 + fr) * 8];
        acc[nf] = __builtin_amdgcn_mfma_f32_16x16x32_bf16(af[kt], bfr, acc[nf], 0, 0, 0);
      }
    }
    if (ch + 1 < NCH) LOADA(m0 + 16);     // next chunk's loads fly under epilogue

    // ---- epilogue: two 8-row passes through per-wave scratch ----
#pragma unroll
    for (int p = 0; p < 2; ++p) {
      const long gr0 = m0 + p * 8;
      if ((kq >> 1) == p) {               // phase1: scatter-activate into scratch
        const int lr = (kq & 1) * 4;
#pragma unroll
        for (int rr = 0; rr < 4; ++rr) {
          const int row = lr + rr;
          float mf = 1.f;
          if (EPI == 1) mf = (mask[gr0 + row] != 0) ? 1.f : 0.f;
#pragma unroll
          for (int nf = 0; nf < NF; ++nf) {
            const float c = acc[nf][rr];
            float val;
            if (EPI == 1) val = hside ? ftanh(c + b0[nf]) * mf
                                      : fsigmoid(c + b1g[nf]);
            else          val = c + b0[nf];
            sc[row * SCS + nf * 16 + fr] = (bf16)val;
          }
        }
      }
      // make phase1's exec-masked DS writes visible before phase2's reads
      asm volatile("s_waitcnt lgkmcnt(0)" ::: "memory");
      __builtin_amdgcn_sched_barrier(0);
      {                                   // phase2: coalesced readback + store
        const int ngr = NCOL / 8;
        const bool act = (lane < 8 * ngr);
        const int prow = lane / ngr, pcol = (lane % ngr) * 8;
        if (act) {
          const long gm = gr0 + prow;
          bf16x8 v = *(const bf16x8*)&sc[prow * SCS + pcol];
          if (hside) *(bf16x8*)&out0[gm * H_ + n0 + pcol] = v;
          else       *(bf16x8*)&out1[gm * H_ + (n0 - H_) + pcol] = v;
        }
      }
      asm volatile("s_waitcnt lgkmcnt(0)" ::: "memory");   // reads done before next p's writes
      __builtin_amdgcn_sched_barrier(0);
    }
  }
#undef LOADA
}

// ======== pw GEMM: round-8 kernel VERBATIM (known passing) ========
// 128x128 tile, BK=32, 8 waves; 2-deep LDS dbuf, counted vmcnt + raw barrier.
// EPI==2: pointwise u epilogue + fused scan1.
template<int KDIM, int EPI>
__global__ __launch_bounds__(512, 5)
void k_gemm(const bf16* __restrict__ A, const bf16* __restrict__ Bw,
            const int* __restrict__ mask,
            const float* __restrict__ bias0, const float* __restrict__ bias1,
            const bf16* __restrict__ hbuf, const bf16* __restrict__ gbuf,
            const float* __restrict__ A_log, const float* __restrict__ Bp,
            float* __restrict__ Ac, float* __restrict__ Bc,
            bf16* __restrict__ out0, bf16* __restrict__ out1, int Ntiles)
{
  extern __shared__ char smem_raw[];            // 34816 B (2x16KB staging | epi tile)
  bf16* tile = (bf16*)smem_raw;

  const int t = threadIdx.x;
  const int w = t >> 6, lane = t & 63;
  const int nwg = gridDim.x;                    // XCD-aware swizzle (nwg % 8 == 0)
  const int wg = (blockIdx.x & 7) * (nwg >> 3) + (blockIdx.x >> 3);
  const int bn0 = (wg % Ntiles) * 128;
  const int bm0 = (wg / Ntiles) * 128;
  const int wm = w >> 2, wn = w & 3;            // 2 x 4 wave grid: 64-row x 32-col
  const int fr = lane & 15, kq = lane >> 4;
  constexpr int NT = KDIM / 32;

  const bf16* Ag = A  + (long)(bm0 + (t >> 2)) * KDIM + (t & 3) * 8;
  const bf16* Bg = Bw + (long)(bn0 + (t >> 2)) * KDIM + (t & 3) * 8;

  f32x4 acc[4][2];
#pragma unroll
  for (int i = 0; i < 4; ++i)
#pragma unroll
    for (int j = 0; j < 2; ++j) acc[i][j] = (f32x4){0.f, 0.f, 0.f, 0.f};

#define STAGE(tt)                                                           \
  { char* _b = smem_raw + ((tt) & 1) * 16384;                               \
    gload_lds16(Ag + (tt) * 32, (bf16*)_b + t * 8);                         \
    gload_lds16(Bg + (tt) * 32, (bf16*)(_b + 8192) + t * 8); }

  STAGE(0); STAGE(1);

#pragma unroll
  for (int kt = 0; kt < NT; ++kt) {
    if (kt + 1 < NT) asm volatile("s_waitcnt vmcnt(2)" ::: "memory");
    else             asm volatile("s_waitcnt vmcnt(0)" ::: "memory");
    __builtin_amdgcn_s_barrier();

    const bf16* As = (const bf16*)(smem_raw + (kt & 1) * 16384);
    const bf16* Bs = As + 4096;
    bf16x8 af[4], bfr[2];
#pragma unroll
    for (int mi = 0; mi < 4; ++mi)
      af[mi] = *(const bf16x8*)&As[(wm * 64 + mi * 16 + fr) * 32 + kq * 8];
#pragma unroll
    for (int ni = 0; ni < 2; ++ni)
      bfr[ni] = *(const bf16x8*)&Bs[(wn * 32 + ni * 16 + fr) * 32 + kq * 8];

    asm volatile("s_waitcnt lgkmcnt(0)" ::: "memory");
    __builtin_amdgcn_s_barrier();

    if (kt + 2 < NT) STAGE(kt + 2);

#pragma unroll
    for (int mi = 0; mi < 4; ++mi)
#pragma unroll
      for (int ni = 0; ni < 2; ++ni)
        acc[mi][ni] = __builtin_amdgcn_mfma_f32_16x16x32_bf16(af[mi], bfr[ni], acc[mi][ni], 0, 0, 0);
  }
#undef STAGE

  __syncthreads();

  const bool hside = (EPI != 1) || (bn0 < H_);
#pragma unroll
  for (int mi = 0; mi < 4; ++mi) {
#pragma unroll
    for (int rr = 0; rr < 4; ++rr) {
      const int row = wm * 64 + mi * 16 + kq * 4 + rr;
      const int gm = bm0 + row;
      float mf = 1.f;
      if (EPI == 1) mf = (mask[gm] != 0) ? 1.f : 0.f;
#pragma unroll
      for (int ni = 0; ni < 2; ++ni) {
        const int col = wn * 32 + ni * 16 + fr;
        float c = acc[mi][ni][rr];
        float val;
        if (EPI == 1) {
          const int gn = bn0 + col;
          val = hside ? ftanh(c + bias0[gn]) * mf
                      : fsigmoid(c + bias1[gn - H_]);
        } else {
          val = c + bias0[bn0 + col];
        }
        tile[row * TPAD + col] = (bf16)val;
      }
    }
  }
  __syncthreads();

  const int pr = t >> 4;
  const int pc = (t & 15) * 8;
#pragma unroll
  for (int rr = 0; rr < 4; ++rr) {
    const int row = pr + rr * 32;
    const long gm = bm0 + row;
    bf16x8 v = *(const bf16x8*)&tile[row * TPAD + pc];
    if (EPI == 1) {
      if (hside) *(bf16x8*)&out0[gm * H_ + bn0 + pc] = v;
      else       *(bf16x8*)&out1[gm * H_ + (bn0 - H_) + pc] = v;
    } else {
      bf16x8 hb = *(const bf16x8*)&hbuf[gm * H_ + bn0 + pc];
      bf16x8 o;
#pragma unroll
      for (int k = 0; k < 8; ++k) {
        float s = (float)v[k] + (float)hb[k];
        o[k] = (bf16)fsilu(s);
      }
      *(bf16x8*)&out0[gm * H_ + bn0 + pc] = o;
      *(bf16x8*)&tile[row * TPAD + pc] = o;
    }
  }

  if constexpr (EPI == 2) {
    __syncthreads();
    const int c_idx = t >> 7;
    const int col   = t & 127;
    const int gcol  = bn0 + col;
    const int bIdx  = bm0 >> 12;
    const int s0    = bm0 & (S_ - 1);
    const int chunk = (s0 >> 5) + c_idx;
    const int* mrow = mask + bIdx * S_ + s0 + c_idx * 32;
    const float aexp = RCPF(1.f + EXP2F(L2E * A_log[gcol]));
    const float bp = Bp[gcol];
    const bf16* grow = gbuf + (long)(bm0 + c_idx * 32) * H_ + gcol;
    float At = 1.f, Bt = 0.f;
#pragma unroll 4
    for (int sl = 0; sl < LCH; ++sl) {
      float uv = (float)tile[(c_idx * 32 + sl) * TPAD + col];
      float gv = (float)grow[(long)sl * H_];
      bool mm = mrow[sl] != 0;
      float a_s = mm ? gv * aexp : 1.f;
      float b_s = mm ? (1.f - gv) * (bp * uv) : 0.f;
      At = a_s * At;
      Bt = fmaf(a_s, Bt, b_s);
    }
    long o = ((long)chunk * B_ + bIdx) * H_ + gcol;
    Ac[o] = At; Bc[o] = Bt;
  }
}

// ---------------- depthwise conv K=3 (r8 verbatim) ----------------
__global__ void k_dwconv(const bf16* __restrict__ h, const float* __restrict__ dww,
                         const float* __restrict__ dwb, bf16* __restrict__ hc)
{
  long idx = (long)blockIdx.x * blockDim.x + threadIdx.x;
  long m = idx >> 6;
  int h8 = ((int)idx & 63) << 3;
  int s = (int)(m & (S_ - 1));
  bf16x8 c0, c1, c2;
#pragma unroll
  for (int j = 0; j < 8; ++j) { c0[j] = (bf16)0.f; c2[j] = (bf16)0.f; }
  if (s > 0)        c0 = *(const bf16x8*)(h + (m - 1) * H_ + h8);
  c1 = *(const bf16x8*)(h + m * H_ + h8);
  if (s < S_ - 1)   c2 = *(const bf16x8*)(h + (m + 1) * H_ + h8);
  bf16x8 o;
#pragma unroll
  for (int j = 0; j < 8; ++j) {
    int hh = h8 + j;
    float v = (float)c0[j] * dww[hh * 3 + 0] + (float)c1[j] * dww[hh * 3 + 1]
            + (float)c2[j] * dww[hh * 3 + 2] + dwb[hh];
    o[j] = (bf16)v;
  }
  *(bf16x8*)(hc + m * H_ + h8) = o;
}

// ---------------- scan passes 2 and 3 (r8 verbatim) ----------------
__global__ __launch_bounds__(256)
void k_scan2(const float* __restrict__ Ac, const float* __restrict__ Bc,
             float* __restrict__ Sin)
{
  int tid = blockIdx.x * 256 + threadIdx.x;
  int b = tid >> 9, h = tid & (H_ - 1);
  const long stride = (long)B_ * H_;
  long o = (long)b * H_ + h;
  float st = 0.f;
  float a = Ac[o], bb = Bc[o];
  for (int c = 0; c < CCH; ++c) {
    float an = 0.f, bn = 0.f;
    if (c + 1 < CCH) { an = Ac[o + stride]; bn = Bc[o + stride]; }
    Sin[o] = st;
    st = fmaf(a, st, bb);
    a = an; bb = bn; o += stride;
  }
}

__global__ __launch_bounds__(256)
void k_scan3(const bf16* __restrict__ u, const bf16* __restrict__ g,
             const int* __restrict__ mask, const float* __restrict__ A_log,
             const float* __restrict__ Bp, const float* __restrict__ Cp,
             const float* __restrict__ Sin,
             const float* __restrict__ ln_g, const float* __restrict__ ln_b,
             float* __restrict__ out)
{
  const int wv = threadIdx.x >> 6, lane = threadIdx.x & 63;
  const int c = blockIdx.x * 4 + wv;
  const int b = blockIdx.y;
  const int h0 = lane * 8;

  float aexp[8], bp[8], cp[8], lg[8], lb[8], st[8];
#pragma unroll
  for (int j = 0; j < 8; ++j) {
    aexp[j] = RCPF(1.f + EXP2F(L2E * A_log[h0 + j]));
    bp[j] = Bp[h0 + j]; cp[j] = Cp[h0 + j];
    lg[j] = ln_g[h0 + j]; lb[j] = ln_b[h0 + j];
    st[j] = Sin[((long)c * B_ + b) * H_ + h0 + j];
  }

  const long base = ((long)b * S_ + (long)c * LCH) * H_ + h0;
  const int* mrow = mask + b * S_ + c * LCH;

  bf16x8 uv = *(const bf16x8*)(u + base);
  bf16x8 gv = *(const bf16x8*)(g + base);
  int mm = mrow[0];

  for (int sl = 0; sl < LCH; ++sl) {
    bf16x8 un, gn; int mn = 0;
    if (sl + 1 < LCH) {
      un = *(const bf16x8*)(u + base + (long)(sl + 1) * H_);
      gn = *(const bf16x8*)(g + base + (long)(sl + 1) * H_);
      mn = mrow[sl + 1];
    }
    const bool m = mm != 0;
    float y[8], sum = 0.f, sq = 0.f;
#pragma unroll
    for (int j = 0; j < 8; ++j) {
      float uu = (float)uv[j], gg = (float)gv[j];
      float a_s = m ? gg * aexp[j] : 1.f;
      float b_s = m ? (1.f - gg) * (bp[j] * uu) : 0.f;
      st[j] = fmaf(a_s, st[j], b_s);
      y[j] = st[j] * cp[j];
      sum += y[j];
      sq = fmaf(y[j], y[j], sq);
    }
#pragma unroll
    for (int off = 32; off; off >>= 1) {
      sum += __shfl_xor(sum, off);
      sq  += __shfl_xor(sq, off);
    }
    const float mu = sum * (1.f / H_);
    const float var = sq * (1.f / H_) - mu * mu;
    const float rs = rsqrtf(var + 1e-5f);
    const long ob = base + (long)sl * H_;
    f32x4 o0, o1;
#pragma unroll
    for (int j = 0; j < 4; ++j) o0[j] = (y[j] - mu) * rs * lg[j] + lb[j];
#pragma unroll
    for (int j = 0; j < 4; ++j) o1[j] = (y[4 + j] - mu) * rs * lg[4 + j] + lb[4 + j];
    *(f32x4*)(out + ob) = o0;
    *(f32x4*)(out + ob + 4) = o1;
    uv = un; gv = gn; mm = mn;
  }
}

// ---------------- launch ----------------
extern "C" void kernel_launch(void* const* d_in, const int* in_sizes, int n_in,
                              void* d_out, int out_size, void* d_ws, size_t ws_size,
                              hipStream_t stream)
{
  const float* x      = (const float*)d_in[0];
  const int*   mask   = (const int*)d_in[1];
  const float* in_w   = (const float*)d_in[2];
  const float* in_b   = (const float*)d_in[3];
  const float* gate_w = (const float*)d_in[4];
  const float* gate_b = (const float*)d_in[5];
  const float* dw_w   = (const float*)d_in[6];
  const float* dw_b   = (const float*)d_in[7];
  const float* pw_w   = (const float*)d_in[8];
  const float* pw_b   = (const float*)d_in[9];
  const float* ln_g   = (const float*)d_in[10];
  const float* ln_b   = (const float*)d_in[11];
  const float* A_log  = (const float*)d_in[12];
  const float* Bp     = (const float*)d_in[13];
  const float* Cp     = (const float*)d_in[14];

  // workspace layout (needs ~316 MB)
  char* ws = (char*)d_ws;
  bf16*  xb  = (bf16*)(ws + 0L);           // 33,554,432 B
  bf16*  h   = (bf16*)(ws + 33554432L);    // 67,108,864 B
  bf16*  hc  = (bf16*)(ws + 100663296L);   // 67,108,864 B
  bf16*  u   = (bf16*)(ws + 167772160L);   // 67,108,864 B
  bf16*  g   = (bf16*)(ws + 234881024L);   // 67,108,864 B
  bf16*  w1  = (bf16*)(ws + 301989888L);   // 524,288 B (in_w ++ gate_w)
  bf16*  pw  = (bf16*)(ws + 302514176L);   // 524,288 B
  float* Ac  = (float*)(ws + 303038464L);  // 4,194,304 B
  float* Bc  = (float*)(ws + 307232768L);  // 4,194,304 B
  float* Sin = (float*)(ws + 311427072L);  // 4,194,304 B
  float* out = (float*)d_out;

  k_cast_x<<<8192, 256, 0, stream>>>(x, xb, (int)(BSD_ / 8));
  k_cast_w<<<2048, 256, 0, stream>>>(in_w, gate_w, pw_w, w1, pw);

  // proj: weight-stationary, K=256, NCOL=64, 16 n-blocks x 32 m-slices
  // LDS: 64*256*2 + 8*(8*72*2) = 32768 + 9216 = 41984 B (<= 65536)
  k_wgemm<256, 1, 16, 16, 64><<<512, 512, 41984, stream>>>(
      xb, w1, mask, in_b, gate_b, h, g);

  k_dwconv<<<16384, 256, 0, stream>>>(h, dw_w, dw_b, hc);

  // pw: r8 kernel, M=65536, N=512, K=512 (+ fused scan1); LDS 34816 B
  k_gemm<512, 2><<<512 * 4, 512, 34816, stream>>>(
      hc, pw, mask, pw_b, nullptr, h, g, A_log, Bp,
      Ac, Bc, u, nullptr, 4);

  k_scan2<<<32, 256, 0, stream>>>(Ac, Bc, Sin);
  k_scan3<<<dim3(CCH / 4, B_), 256, 0, stream>>>(
      u, g, mask, A_log, Bp, Cp, Sin, ln_g, ln_b, out);
}

// Round 16
// 347.720 us; speedup vs baseline: 1.0215x; 1.0215x over previous
//
#include <hip/hip_runtime.h>
#include <hip/hip_bf16.h>
#include <math.h>

// Problem dims
#define B_  16
#define S_  4096
#define D_  256
#define H_  512
#define BS_ 65536           // B_*S_
#define CCH 128             // scan chunks
#define LCH 32              // chunk length
#define TPAD 136            // epilogue tile stride (272B row, 16B multiple)

typedef __bf16 bf16;
typedef __bf16 bf16x8 __attribute__((ext_vector_type(8)));
typedef float  f32x4  __attribute__((ext_vector_type(4)));

#define AS1 __attribute__((address_space(1)))
#define AS3 __attribute__((address_space(3)))

__device__ __forceinline__ void gload_lds16(const void* g, void* l) {
  __builtin_amdgcn_global_load_lds((const AS1 void*)g, (AS3 void*)l, 16, 0, 0);
}

// ---- fast transcendentals ----
#if __has_builtin(__builtin_amdgcn_exp2f)
#define EXP2F __builtin_amdgcn_exp2f
#else
#define EXP2F exp2f
#endif
#if __has_builtin(__builtin_amdgcn_rcpf)
#define RCPF __builtin_amdgcn_rcpf
#else
#define RCPF(x) (1.f/(x))
#endif
#define L2E 1.4426950408889634f

__device__ __forceinline__ float fsigmoid(float x) {
  return RCPF(1.f + EXP2F(-L2E * x));
}
__device__ __forceinline__ float ftanh(float x) {
  return 2.f * RCPF(1.f + EXP2F(-2.f * L2E * x)) - 1.f;
}
__device__ __forceinline__ float fsilu(float x) {
  return x * RCPF(1.f + EXP2F(-L2E * x));
}

// ---------------- weight cast ----------------
__global__ void k_cast_w(const float* __restrict__ in_w, const float* __restrict__ gate_w,
                         const float* __restrict__ pw_w,
                         bf16* __restrict__ w1, bf16* __restrict__ pw) {
  int i = blockIdx.x * blockDim.x + threadIdx.x;
  const int HD = H_ * D_;           // 131072
  if (i < HD)            w1[i] = (bf16)in_w[i];
  else if (i < 2 * HD)   w1[i] = (bf16)gate_w[i - HD];
  else {
    int j = i - 2 * HD;
    if (j < H_ * H_)     pw[j] = (bf16)pw_w[j];
  }
}

// ======== proj GEMM: 128x128 tile, BK=32, 8 waves, FUSED x-cast staging ========
// A staged by registers (2x float4 -> cvt bf16x8 -> ds_write_b128), B via
// global_load_lds. Single __syncthreads per K-tile (r3 discipline, compiler-
// managed waits). Epilogue: tanh*mask -> h, sigmoid -> g (r8 verbatim).
__global__ __launch_bounds__(512, 4)
void k_gemm1(const float* __restrict__ X, const bf16* __restrict__ Bw,
             const int* __restrict__ mask,
             const float* __restrict__ bias0, const float* __restrict__ bias1,
             bf16* __restrict__ out0, bf16* __restrict__ out1, int Ntiles)
{
  extern __shared__ char smem[];                // 34816 B
  bf16* tile = (bf16*)smem;
  const int t = threadIdx.x;
  const int w = t >> 6, lane = t & 63;
  const int nwg = gridDim.x;                    // %8==0
  const int wg = (blockIdx.x & 7) * (nwg >> 3) + (blockIdx.x >> 3);
  const int bn0 = (wg % Ntiles) * 128;
  const int bm0 = (wg / Ntiles) * 128;
  const int wm = w >> 2, wn = w & 3;
  const int fr = lane & 15, kq = lane >> 4;
  constexpr int KDIM = 256, NT = 8;

  const float* Xg = X + (long)(bm0 + (t >> 2)) * KDIM + (t & 3) * 8;
  const bf16*  Bg = Bw + (long)(bn0 + (t >> 2)) * KDIM + (t & 3) * 8;

  f32x4 acc[4][2];
#pragma unroll
  for (int i = 0; i < 4; ++i)
#pragma unroll
    for (int j = 0; j < 2; ++j) acc[i][j] = (f32x4){0.f, 0.f, 0.f, 0.f};

#define STAGE1(tt)                                                          \
  { const int _bi = (tt) & 1;                                               \
    f32x4 xa = *(const f32x4*)(Xg + (tt) * 32);                             \
    f32x4 xb = *(const f32x4*)(Xg + (tt) * 32 + 4);                         \
    bf16x8 av;                                                              \
    _Pragma("unroll")                                                       \
    for (int j = 0; j < 4; ++j) { av[j] = (bf16)xa[j]; av[4+j] = (bf16)xb[j]; } \
    *(bf16x8*)((bf16*)(smem + _bi * 16384) + t * 8) = av;                   \
    gload_lds16(Bg + (tt) * 32, (bf16*)(smem + _bi * 16384 + 8192) + t * 8); }

  STAGE1(0);
#pragma unroll
  for (int kt = 0; kt < NT; ++kt) {
    __syncthreads();                            // publishes buf[kt&1]
    if (kt + 1 < NT) STAGE1(kt + 1);            // into buf[kt^1] (readers done)
    const bf16* As = (const bf16*)(smem + (kt & 1) * 16384);
    const bf16* Bs = As + 4096;
    bf16x8 af[4], bfr[2];
#pragma unroll
    for (int mi = 0; mi < 4; ++mi)
      af[mi] = *(const bf16x8*)&As[(wm * 64 + mi * 16 + fr) * 32 + kq * 8];
#pragma unroll
    for (int ni = 0; ni < 2; ++ni)
      bfr[ni] = *(const bf16x8*)&Bs[(wn * 32 + ni * 16 + fr) * 32 + kq * 8];
#pragma unroll
    for (int mi = 0; mi < 4; ++mi)
#pragma unroll
      for (int ni = 0; ni < 2; ++ni)
        acc[mi][ni] = __builtin_amdgcn_mfma_f32_16x16x32_bf16(af[mi], bfr[ni], acc[mi][ni], 0, 0, 0);
  }
#undef STAGE1

  __syncthreads();

  // ---- epilogue (r8 EPI==1 verbatim) ----
  const bool hside = (bn0 < H_);
#pragma unroll
  for (int mi = 0; mi < 4; ++mi) {
#pragma unroll
    for (int rr = 0; rr < 4; ++rr) {
      const int row = wm * 64 + mi * 16 + kq * 4 + rr;
      const int gm = bm0 + row;
      const float mf = (mask[gm] != 0) ? 1.f : 0.f;
#pragma unroll
      for (int ni = 0; ni < 2; ++ni) {
        const int col = wn * 32 + ni * 16 + fr;
        const int gn = bn0 + col;
        const float c = acc[mi][ni][rr];
        const float val = hside ? ftanh(c + bias0[gn]) * mf
                                : fsigmoid(c + bias1[gn - H_]);
        tile[row * TPAD + col] = (bf16)val;
      }
    }
  }
  __syncthreads();

  const int pr = t >> 4;
  const int pc = (t & 15) * 8;
#pragma unroll
  for (int rr = 0; rr < 4; ++rr) {
    const int row = pr + rr * 32;
    const long gm = bm0 + row;
    bf16x8 v = *(const bf16x8*)&tile[row * TPAD + pc];
    if (hside) *(bf16x8*)&out0[gm * H_ + bn0 + pc] = v;
    else       *(bf16x8*)&out1[gm * H_ + (bn0 - H_) + pc] = v;
  }
}

// ======== pw GEMM: 128x128 tile, BK=32, 8 waves, FUSED depthwise-conv staging ========
// A-tile = dwconv(h) computed in registers during staging (3 bf16x8 row loads +
// f32 taps from LDS table) -> ds_write_b128. B via global_load_lds. Single
// __syncthreads per K-tile. Epilogue: u = silu(pc + pw_b + h) + fused scan1
// (r8 EPI==2 verbatim). hc never materialized.
__global__ __launch_bounds__(512, 4)
void k_gemm2(const bf16* __restrict__ h, const bf16* __restrict__ Bw,
             const int* __restrict__ mask, const float* __restrict__ pwb,
             const float* __restrict__ dww, const float* __restrict__ dwb,
             const bf16* __restrict__ gbuf, const float* __restrict__ A_log,
             const float* __restrict__ Bp,
             float* __restrict__ Ac, float* __restrict__ Bc,
             bf16* __restrict__ u, int Ntiles)
{
  extern __shared__ char smem[];                // 43008 B: [0,34816) tile/staging, then weights
  bf16* tile = (bf16*)smem;
  float* wt = (float*)(smem + 34816);           // [3][512] f32 (tap-major)
  float* wb = wt + 1536;                        // [512] f32
  const int t = threadIdx.x;
  const int w = t >> 6, lane = t & 63;
  const int nwg = gridDim.x;                    // %8==0
  const int wg = (blockIdx.x & 7) * (nwg >> 3) + (blockIdx.x >> 3);
  const int bn0 = (wg % Ntiles) * 128;
  const int bm0 = (wg / Ntiles) * 128;
  const int wm = w >> 2, wn = w & 3;
  const int fr = lane & 15, kq = lane >> 4;
  constexpr int KDIM = 512, NT = 16;

  // preload conv weight tables (tap-major so an 8-ch slot is 2 contiguous f32x4)
  for (int i = t; i < 1536; i += 512) wt[i] = dww[(i & 511) * 3 + (i >> 9)];
  if (t < 512) wb[t] = dwb[t];

  const int sr = t >> 2, sc8 = (t & 3) * 8;
  const long gm = bm0 + sr;
  const int s = (int)(gm & (S_ - 1));
  const bool has_m = (s > 0), has_p = (s < S_ - 1);
  const bf16* hp = h + gm * (long)H_ + sc8;
  const bf16* Bg = Bw + (long)(bn0 + sr) * KDIM + sc8;

  f32x4 acc[4][2];
#pragma unroll
  for (int i = 0; i < 4; ++i)
#pragma unroll
    for (int j = 0; j < 2; ++j) acc[i][j] = (f32x4){0.f, 0.f, 0.f, 0.f};

  __syncthreads();                              // weight tables ready

#define STAGE2(tt)                                                          \
  { const int _bi = (tt) & 1;                                               \
    const int ch = (tt) * 32 + sc8;                                         \
    bf16x8 a0, a1, a2;                                                      \
    _Pragma("unroll")                                                       \
    for (int j = 0; j < 8; ++j) { a0[j] = (bf16)0.f; a2[j] = (bf16)0.f; }   \
    a1 = *(const bf16x8*)(hp + (tt) * 32);                                  \
    if (has_m) a0 = *(const bf16x8*)(hp + (tt) * 32 - H_);                  \
    if (has_p) a2 = *(const bf16x8*)(hp + (tt) * 32 + H_);                  \
    f32x4 w0a = *(const f32x4*)(wt + ch),        w0b = *(const f32x4*)(wt + ch + 4); \
    f32x4 w1a = *(const f32x4*)(wt + 512 + ch),  w1b = *(const f32x4*)(wt + 512 + ch + 4); \
    f32x4 w2a = *(const f32x4*)(wt + 1024 + ch), w2b = *(const f32x4*)(wt + 1024 + ch + 4); \
    f32x4 ba  = *(const f32x4*)(wb + ch),        bb  = *(const f32x4*)(wb + ch + 4); \
    bf16x8 o;                                                               \
    _Pragma("unroll")                                                       \
    for (int j = 0; j < 4; ++j) {                                           \
      o[j]   = (bf16)((float)a0[j]   * w0a[j] + (float)a1[j]   * w1a[j]     \
                    + (float)a2[j]   * w2a[j] + ba[j]);                     \
      o[4+j] = (bf16)((float)a0[4+j] * w0b[j] + (float)a1[4+j] * w1b[j]     \
                    + (float)a2[4+j] * w2b[j] + bb[j]);                     \
    }                                                                       \
    *(bf16x8*)((bf16*)(smem + _bi * 16384) + t * 8) = o;                    \
    gload_lds16(Bg + (tt) * 32, (bf16*)(smem + _bi * 16384 + 8192) + t * 8); }

  STAGE2(0);
#pragma unroll
  for (int kt = 0; kt < NT; ++kt) {
    __syncthreads();                            // publishes buf[kt&1]
    if (kt + 1 < NT) STAGE2(kt + 1);            // into buf[kt^1]
    const bf16* As = (const bf16*)(smem + (kt & 1) * 16384);
    const bf16* Bs = As + 4096;
    bf16x8 af[4], bfr[2];
#pragma unroll
    for (int mi = 0; mi < 4; ++mi)
      af[mi] = *(const bf16x8*)&As[(wm * 64 + mi * 16 + fr) * 32 + kq * 8];
#pragma unroll
    for (int ni = 0; ni < 2; ++ni)
      bfr[ni] = *(const bf16x8*)&Bs[(wn * 32 + ni * 16 + fr) * 32 + kq * 8];
#pragma unroll
    for (int mi = 0; mi < 4; ++mi)
#pragma unroll
      for (int ni = 0; ni < 2; ++ni)
        acc[mi][ni] = __builtin_amdgcn_mfma_f32_16x16x32_bf16(af[mi], bfr[ni], acc[mi][ni], 0, 0, 0);
  }
#undef STAGE2

  __syncthreads();

  // ---- epilogue phase 1: c + pw_b into tile ----
#pragma unroll
  for (int mi = 0; mi < 4; ++mi) {
#pragma unroll
    for (int rr = 0; rr < 4; ++rr) {
      const int row = wm * 64 + mi * 16 + kq * 4 + rr;
#pragma unroll
      for (int ni = 0; ni < 2; ++ni) {
        const int col = wn * 32 + ni * 16 + fr;
        tile[row * TPAD + col] = (bf16)(acc[mi][ni][rr] + pwb[bn0 + col]);
      }
    }
  }
  __syncthreads();

  // ---- epilogue phase 2: u = silu(. + h), coalesced; keep u in tile ----
  const int pr = t >> 4;
  const int pc = (t & 15) * 8;
#pragma unroll
  for (int rr = 0; rr < 4; ++rr) {
    const int row = pr + rr * 32;
    const long gmr = bm0 + row;
    bf16x8 v = *(const bf16x8*)&tile[row * TPAD + pc];
    bf16x8 hb = *(const bf16x8*)&h[gmr * H_ + bn0 + pc];
    bf16x8 o;
#pragma unroll
    for (int k = 0; k < 8; ++k) o[k] = (bf16)fsilu((float)v[k] + (float)hb[k]);
    *(bf16x8*)&u[gmr * H_ + bn0 + pc] = o;
    *(bf16x8*)&tile[row * TPAD + pc] = o;
  }

  // ---- fused scan1: per-chunk (A,B) reduction from the u tile ----
  __syncthreads();
  const int c_idx = t >> 7;
  const int col   = t & 127;
  const int gcol  = bn0 + col;
  const int bIdx  = bm0 >> 12;
  const int s0    = bm0 & (S_ - 1);
  const int chunk = (s0 >> 5) + c_idx;
  const int* mrow = mask + bIdx * S_ + s0 + c_idx * 32;
  const float aexp = RCPF(1.f + EXP2F(L2E * A_log[gcol]));
  const float bp = Bp[gcol];
  const bf16* grow = gbuf + (long)(bm0 + c_idx * 32) * H_ + gcol;
  float At = 1.f, Bt = 0.f;
#pragma unroll 4
  for (int sl = 0; sl < LCH; ++sl) {
    float uv = (float)tile[(c_idx * 32 + sl) * TPAD + col];
    float gv = (float)grow[(long)sl * H_];
    bool mm = mrow[sl] != 0;
    float a_s = mm ? gv * aexp : 1.f;
    float b_s = mm ? (1.f - gv) * (bp * uv) : 0.f;
    At = a_s * At;
    Bt = fmaf(a_s, Bt, b_s);
  }
  long o = ((long)chunk * B_ + bIdx) * H_ + gcol;
  Ac[o] = At; Bc[o] = Bt;
}

// ---------------- scan passes 2 and 3 (r8 verbatim) ----------------
__global__ __launch_bounds__(256)
void k_scan2(const float* __restrict__ Ac, const float* __restrict__ Bc,
             float* __restrict__ Sin)
{
  int tid = blockIdx.x * 256 + threadIdx.x;
  int b = tid >> 9, h = tid & (H_ - 1);
  const long stride = (long)B_ * H_;
  long o = (long)b * H_ + h;
  float st = 0.f;
  float a = Ac[o], bb = Bc[o];
  for (int c = 0; c < CCH; ++c) {
    float an = 0.f, bn = 0.f;
    if (c + 1 < CCH) { an = Ac[o + stride]; bn = Bc[o + stride]; }
    Sin[o] = st;
    st = fmaf(a, st, bb);
    a = an; bb = bn; o += stride;
  }
}

__global__ __launch_bounds__(256)
void k_scan3(const bf16* __restrict__ u, const bf16* __restrict__ g,
             const int* __restrict__ mask, const float* __restrict__ A_log,
             const float* __restrict__ Bp, const float* __restrict__ Cp,
             const float* __restrict__ Sin,
             const float* __restrict__ ln_g, const float* __restrict__ ln_b,
             float* __restrict__ out)
{
  const int wv = threadIdx.x >> 6, lane = threadIdx.x & 63;
  const int c = blockIdx.x * 4 + wv;
  const int b = blockIdx.y;
  const int h0 = lane * 8;

  float aexp[8], bp[8], cp[8], lg[8], lb[8], st[8];
#pragma unroll
  for (int j = 0; j < 8; ++j) {
    aexp[j] = RCPF(1.f + EXP2F(L2E * A_log[h0 + j]));
    bp[j] = Bp[h0 + j]; cp[j] = Cp[h0 + j];
    lg[j] = ln_g[h0 + j]; lb[j] = ln_b[h0 + j];
    st[j] = Sin[((long)c * B_ + b) * H_ + h0 + j];
  }

  const long base = ((long)b * S_ + (long)c * LCH) * H_ + h0;
  const int* mrow = mask + b * S_ + c * LCH;

  bf16x8 uv = *(const bf16x8*)(u + base);
  bf16x8 gv = *(const bf16x8*)(g + base);
  int mm = mrow[0];

  for (int sl = 0; sl < LCH; ++sl) {
    bf16x8 un, gn; int mn = 0;
    if (sl + 1 < LCH) {
      un = *(const bf16x8*)(u + base + (long)(sl + 1) * H_);
      gn = *(const bf16x8*)(g + base + (long)(sl + 1) * H_);
      mn = mrow[sl + 1];
    }
    const bool m = mm != 0;
    float y[8], sum = 0.f, sq = 0.f;
#pragma unroll
    for (int j = 0; j < 8; ++j) {
      float uu = (float)uv[j], gg = (float)gv[j];
      float a_s = m ? gg * aexp[j] : 1.f;
      float b_s = m ? (1.f - gg) * (bp[j] * uu) : 0.f;
      st[j] = fmaf(a_s, st[j], b_s);
      y[j] = st[j] * cp[j];
      sum += y[j];
      sq = fmaf(y[j], y[j], sq);
    }
#pragma unroll
    for (int off = 32; off; off >>= 1) {
      sum += __shfl_xor(sum, off);
      sq  += __shfl_xor(sq, off);
    }
    const float mu = sum * (1.f / H_);
    const float var = sq * (1.f / H_) - mu * mu;
    const float rs = rsqrtf(var + 1e-5f);
    const long ob = base + (long)sl * H_;
    f32x4 o0, o1;
#pragma unroll
    for (int j = 0; j < 4; ++j) o0[j] = (y[j] - mu) * rs * lg[j] + lb[j];
#pragma unroll
    for (int j = 0; j < 4; ++j) o1[j] = (y[4 + j] - mu) * rs * lg[4 + j] + lb[4 + j];
    *(f32x4*)(out + ob) = o0;
    *(f32x4*)(out + ob + 4) = o1;
    uv = un; gv = gn; mm = mn;
  }
}

// ---------------- launch ----------------
extern "C" void kernel_launch(void* const* d_in, const int* in_sizes, int n_in,
                              void* d_out, int out_size, void* d_ws, size_t ws_size,
                              hipStream_t stream)
{
  const float* x      = (const float*)d_in[0];
  const int*   mask   = (const int*)d_in[1];
  const float* in_w   = (const float*)d_in[2];
  const float* in_b   = (const float*)d_in[3];
  const float* gate_w = (const float*)d_in[4];
  const float* gate_b = (const float*)d_in[5];
  const float* dw_w   = (const float*)d_in[6];
  const float* dw_b   = (const float*)d_in[7];
  const float* pw_w   = (const float*)d_in[8];
  const float* pw_b   = (const float*)d_in[9];
  const float* ln_g   = (const float*)d_in[10];
  const float* ln_b   = (const float*)d_in[11];
  const float* A_log  = (const float*)d_in[12];
  const float* Bp     = (const float*)d_in[13];
  const float* Cp     = (const float*)d_in[14];

  // workspace layout (~316 MB available; xb/hc slots now unused)
  char* ws = (char*)d_ws;
  bf16*  h   = (bf16*)(ws + 33554432L);    // 67,108,864 B
  bf16*  u   = (bf16*)(ws + 167772160L);   // 67,108,864 B
  bf16*  g   = (bf16*)(ws + 234881024L);   // 67,108,864 B
  bf16*  w1  = (bf16*)(ws + 301989888L);   // 524,288 B (in_w ++ gate_w)
  bf16*  pw  = (bf16*)(ws + 302514176L);   // 524,288 B
  float* Ac  = (float*)(ws + 303038464L);  // 4,194,304 B
  float* Bc  = (float*)(ws + 307232768L);  // 4,194,304 B
  float* Sin = (float*)(ws + 311427072L);  // 4,194,304 B
  float* out = (float*)d_out;

  k_cast_w<<<2048, 256, 0, stream>>>(in_w, gate_w, pw_w, w1, pw);

  // proj (fused x-cast): M=65536, N=1024, K=256; LDS 34816 B; Ntiles=8
  k_gemm1<<<512 * 8, 512, 34816, stream>>>(
      x, w1, mask, in_b, gate_b, h, g, 8);

  // pw (fused dwconv + scan1): M=65536, N=512, K=512; LDS 43008 B; Ntiles=4
  k_gemm2<<<512 * 4, 512, 43008, stream>>>(
      h, pw, mask, pw_b, dw_w, dw_b, g, A_log, Bp,
      Ac, Bc, u, 4);

  k_scan2<<<32, 256, 0, stream>>>(Ac, Bc, Sin);
  k_scan3<<<dim3(CCH / 4, B_), 256, 0, stream>>>(
      u, g, mask, A_log, Bp, Cp, Sin, ln_g, ln_b, out);
}